// Round 12
// baseline (324.968 us; speedup 1.0000x reference)
//
#include <hip/hip_runtime.h>

// LaplacianPyramidLoss: loss = sum_l mean(|pyr(x)[l] - pyr(t)[l]|)
// Linearity: pyr(x)-pyr(t) = pyr(x-t) -> ONE pyramid of d=x-t.
// R12: BARRIER-FREE per-wave pipelines. Every barrier-synced variant
// (R5/6/9/11) pins at 2.9-3.3 TB/s: loads issue as one burst per block
// period -> in-flight bytes collapse between bursts. Fix: 1 wave per
// block, wave-private dbuf LDS (gload_lds dest is wave-uniform anyway),
// counted per-wave vmcnt (stage(next) -> vmcnt(8) -> compute(cur)) ->
// 10 independent pipelines/CU issuing continuously, zero s_barrier.
// LDS written ONLY by gload_lds, read ONLY by the owning wave -> no
// lgkm hazards. Separable 5x5 (k = g g^T exactly, g = row sums);
// h-pass+v-pass per lane (lane=col, half-waves split rows); borders
// exact via clamped staging addresses + zeroed gaussian taps.
// Waves walk DOWN the image so the 3-row vertical halo is L1/L2-hot.
// Level 2 fuses mean(|down2|): down2 never touches HBM.

constexpr int TPB   = 64;            // ONE wave per block
constexpr int SEG4  = 19;            // float4 per staged row
constexpr int STRIDE = 4 * SEG4;     // 76-float row stride (bank-decoupled)
constexpr int SROWS = 11;            // staged input rows (8 fresh + 3 halo)
constexpr int WOPS  = 4;             // 64-lane x 16B ops (11*19=209 <= 256)
constexpr int BUFSZ = WOPS * 64 * 4; // 1024 floats = 4 KB per buffer

__device__ inline void gload_lds16(const float* g, float* l) {
    auto g1 = (const __attribute__((address_space(1))) void*)g;
    auto l3 = (__attribute__((address_space(3))) void*)l;
    __builtin_amdgcn_global_load_lds(g1, l3, 16, 0, 0);
}

template <bool FUSE, bool LAST, bool WRITE_DOWN>
__global__ __launch_bounds__(TPB)
void lap_wave(const float* __restrict__ A,    // x (lvl0) or cur
              const float* __restrict__ Bp,   // t (lvl0) or nullptr
              const float* __restrict__ w25,  // 5x5 gaussian (channel 0)
              float* __restrict__ down,       // H/2 x W/2 (if WRITE_DOWN)
              float* __restrict__ P,          // partials P[lvl*8+s], [24+s]
              int H, int W, int ntx, int nty, int ntiles, int K, int level)
{
    __shared__ __align__(16) float sA[2][BUFSZ];
    __shared__ __align__(16) float sB[2][FUSE ? BUFSZ : 4];

    const int lane = threadIdx.x;
    const int c    = lane & 31;      // down column within tile
    const int rsub = lane >> 5;      // 0: down rows 0,1   1: down rows 2,3
    const int Hd = H >> 1, Wd = W >> 1;

    // exact 1D factor: g_i = row-sum of w25 (k = g g^T since sum k = T^2)
    float g0, g1v, g2, g3, g4;
    {
        float gg[5];
#pragma unroll
        for (int i = 0; i < 5; ++i) {
            float s = 0.f;
#pragma unroll
            for (int j = 0; j < 5; ++j) s += w25[i*5 + j];
            gg[i] = s;
        }
        g0 = gg[0]; g1v = gg[1]; g2 = gg[2]; g3 = gg[3]; g4 = gg[4];
    }

    // per-lane staging coords (iteration-invariant); tail ops re-read row 10
    int rc_[WOPS], cb_[WOPS];
#pragma unroll
    for (int j = 0; j < WOPS; ++j) {
        const int idx = j*64 + lane;
        const int r = idx / SEG4;
        cb_[j] = 4 * (idx - r*SEG4);
        rc_[j] = r > SROWS-1 ? SROWS-1 : r;
    }

    const int t0 = blockIdx.x * K;
    const int t1 = (t0 + K < ntiles) ? (t0 + K) : ntiles;

    float lsum = 0.f, dsum = 0.f;

    if (t0 < t1) {
        int cn, cx, cy;   // image-channel, strip, row-tile (ry fastest = walk down)
        { const int t = t0; cn = t/(ntx*nty);
          const int r2 = t - cn*ntx*nty; cx = r2/nty; cy = r2 - cx*nty; }

        auto stage = [&](int n, int sx, int ry, int pp) {
            const int gy0 = 8*ry - 2;
            const int gx0 = 64*sx - 4;
            const size_t ib = (size_t)n * H * W;
#pragma unroll
            for (int j = 0; j < WOPS; ++j) {
                int gy = gy0 + rc_[j]; gy = gy < 0 ? 0 : (gy > H-1 ? H-1 : gy);
                int gx = gx0 + cb_[j]; gx = gx < 0 ? 0 : (gx > W-4 ? W-4 : gx);
                const size_t off = ib + (size_t)gy*W + gx;
                gload_lds16(A + off, &sA[pp][j*256]);
                if constexpr (FUSE) gload_lds16(Bp + off, &sB[pp][j*256]);
            }
        };

        auto compute = [&](int n, int sx, int ry, int pp) {
            const float* ax = sA[pp];
            const float* bx = FUSE ? sB[pp] : sA[pp];
            // horizontal edge taps (clamped halo cols are garbage -> zero taps)
            const bool ec = (sx == 0) & (c == 0);
            const float q0 = ec ? 0.f : g0, q1 = ec ? 0.f : g1v;
            const float q4 = ((sx == ntx-1) & (c == 31)) ? 0.f : g4;
            const int rb = 4*rsub;
            float h[7];
#pragma unroll
            for (int s = 0; s < 7; ++s) {
                const float* pa = &ax[(rb + s)*STRIDE + 2*c + 2];
                const float2 A01 = *(const float2*)pa;
                const float2 A23 = *(const float2*)(pa + 2);
                const float2 A45 = *(const float2*)(pa + 4);
                float a0 = A01.x, a1 = A01.y, a2 = A23.x, a3 = A23.y, a4 = A45.x;
                if constexpr (FUSE) {
                    const float* pb = &bx[(rb + s)*STRIDE + 2*c + 2];
                    const float2 B01 = *(const float2*)pb;
                    const float2 B23 = *(const float2*)(pb + 2);
                    const float2 B45 = *(const float2*)(pb + 4);
                    a0 -= B01.x; a1 -= B01.y; a2 -= B23.x; a3 -= B23.y; a4 -= B45.x;
                }
                h[s] = fmaf(q4, a4, fmaf(g3, a3, fmaf(g2, a2, fmaf(q1, a1, q0*a0))));
            }
#pragma unroll
            for (int q = 0; q < 2; ++q) {
                const int r  = 2*rsub + q;      // 0..3 within tile
                const int gr = 4*ry + r;        // global down row
                const float v0 = (gr == 0) ? 0.f : g0;
                const float v1 = (gr == 0) ? 0.f : g1v;
                const float v4 = (gr == Hd-1) ? 0.f : g4;
                const float acc =
                    fmaf(v4, h[2*q+4], fmaf(g3, h[2*q+3],
                    fmaf(g2, h[2*q+2], fmaf(v1, h[2*q+1], v0*h[2*q]))));
                if constexpr (WRITE_DOWN)
                    down[(size_t)n*Hd*Wd + (size_t)gr*Wd + (sx*32 + c)] = acc;
                // lap = cur - up(down): input rows 2gr,2gr+1, cols 2gc,2gc+1
                const int sr = (rb + 2*q + 2)*STRIDE + 2*c + 4;
                const float2 X0 = *(const float2*)&ax[sr];
                const float2 X1 = *(const float2*)&ax[sr + STRIDE];
                float c0 = X0.x, c1 = X0.y, c2 = X1.x, c3 = X1.y;
                if constexpr (FUSE) {
                    const float2 Y0 = *(const float2*)&bx[sr];
                    const float2 Y1 = *(const float2*)&bx[sr + STRIDE];
                    c0 -= Y0.x; c1 -= Y0.y; c2 -= Y1.x; c3 -= Y1.y;
                }
                lsum += fabsf(c0 - acc) + fabsf(c1 - acc)
                      + fabsf(c2 - acc) + fabsf(c3 - acc);
                if constexpr (LAST) dsum += fabsf(acc);
            }
        };

        stage(cn, cx, cy, 0);
        int pp = 0;
        for (int t = t0; t < t1; ++t) {
            int nn = cn, nx = cx, ny = cy + 1;           // next tile (walk down)
            if (ny == nty) { ny = 0; ++nx; if (nx == ntx) { nx = 0; ++nn; } }
            if (t + 1 < t1) {
                stage(nn, nx, ny, pp ^ 1);               // counted pipeline:
                if constexpr (FUSE)                      // next's loads stay
                    asm volatile("s_waitcnt vmcnt(8)" ::: "memory");
                else                                     // in flight, cur's
                    asm volatile("s_waitcnt vmcnt(4)" ::: "memory");
            } else {                                     // are complete
                asm volatile("s_waitcnt vmcnt(0)" ::: "memory");
            }
            compute(cn, cx, cy, pp);
            cn = nn; cx = nx; cy = ny; pp ^= 1;
        }
    }

    // wave reduce -> one spread atomic per wave per level (no block sync!)
#pragma unroll
    for (int off = 32; off > 0; off >>= 1) {
        lsum += __shfl_down(lsum, off);
        if (LAST) dsum += __shfl_down(dsum, off);
    }
    if (lane == 0) {
        atomicAdd(&P[level*8 + (blockIdx.x & 7)], lsum);
        if (LAST) atomicAdd(&P[24 + (blockIdx.x & 7)], dsum);
    }
}

__global__ void finalize_kernel(const float* __restrict__ P,
                                float* __restrict__ out,
                                float inv0, float inv1, float inv2, float inv3)
{
    float s0 = 0.f, s1 = 0.f, s2 = 0.f, s3 = 0.f;
#pragma unroll
    for (int i = 0; i < 8; ++i) {
        s0 += P[i]; s1 += P[8+i]; s2 += P[16+i]; s3 += P[24+i];
    }
    out[0] = s0*inv0 + s1*inv1 + s2*inv2 + s3*inv3;
}

extern "C" void kernel_launch(void* const* d_in, const int* in_sizes, int n_in,
                              void* d_out, int out_size, void* d_ws, size_t ws_size,
                              hipStream_t stream)
{
    const float* x   = (const float*)d_in[0];
    const float* t   = (const float*)d_in[1];
    const float* ker = (const float*)d_in[2];  // (13,1,5,5); channels identical
    float* out = (float*)d_out;

    constexpr int B = 16, C = 13, H = 512, W = 512;
    constexpr int N = B * C;  // 208 image-channels

    // ws: [32 floats partials (pad 256B)] [down0: N*256*256] [down1: N*128*128]
    float* P     = (float*)d_ws;
    float* down0 = (float*)((char*)d_ws + 256);
    float* down1 = down0 + (size_t)N * (H/2) * (W/2);

    hipMemsetAsync(P, 0, 32 * sizeof(float), stream);

    // level 0: FUSE. tiles: ntx=8 strips x nty=64 row-tiles x 208 = 106496.
    // 16KB LDS/1-wave block -> 10 blocks/CU -> grid 2560, K=42.
    {
        const int ntx = (W/2)/32, nty = (H/2)/4, nt = ntx*nty*N;
        const int grid = 2560, K = (nt + grid - 1)/grid;
        lap_wave<true, false, true><<<grid, TPB, 0, stream>>>(
            x, t, ker, down0, P, H, W, ntx, nty, nt, K, 0);
    }
    // level 1: 256 -> 128. 8KB LDS -> 16 blocks/CU -> grid 4096, K=7.
    {
        const int ntx = (W/4)/32, nty = (H/4)/4, nt = ntx*nty*N;
        const int grid = 4096, K = (nt + grid - 1)/grid;
        lap_wave<false, false, true><<<grid, TPB, 0, stream>>>(
            down0, nullptr, ker, down1, P, H/2, W/2, ntx, nty, nt, K, 1);
    }
    // level 2: 128 -> 64 (down2 in-register; fuses mean|down2|). grid 2048, K=4.
    {
        const int ntx = (W/8)/32, nty = (H/8)/4, nt = ntx*nty*N;
        const int grid = 2048, K = (nt + grid - 1)/grid;
        lap_wave<false, true, false><<<grid, TPB, 0, stream>>>(
            down1, nullptr, ker, nullptr, P, H/4, W/4, ntx, nty, nt, K, 2);
    }

    const float inv0 = 1.0f / ((float)N * H * W);
    const float inv1 = 1.0f / ((float)N * (H/2) * (W/2));
    const float inv2 = 1.0f / ((float)N * (H/4) * (W/4));
    const float inv3 = 1.0f / ((float)N * (H/8) * (W/8));
    finalize_kernel<<<1, 1, 0, stream>>>(P, out, inv0, inv1, inv2, inv3);
}

// Round 13
// 221.875 us; speedup vs baseline: 1.4646x; 1.4646x over previous
//
#include <hip/hip_runtime.h>

// LaplacianPyramidLoss: loss = sum_l mean(|pyr(x)[l] - pyr(t)[l]|)
// Linearity: pyr(x)-pyr(t) = pyr(x-t) -> ONE pyramid of d=x-t.
// R13: R11's structure + the T3/T4 counted-vmcnt 3-buffer ring. R11's bug:
// `s_waitcnt vmcnt(0)` at loop top drained the prefetch issued one
// iteration earlier -> pipe empty every tile -> 3 TB/s wall (R5/6/9/11
// all identical). Fix: 3 LDS buffers; per tile: barrier (frees buf t-1),
// stage(t+2), vmcnt(12) [keeps t+1,t+2 = 12 per-wave ops IN FLIGHT,
// retires only tile t's 6 oldest], barrier, compute(t). Staging padded to
// 12 wave-ops, exactly 3 per wave, so per-wave vmcnt counts are uniform.
// ~96 KB/CU continuously in flight vs Little's-law need ~22 KB.
// Level 2 fuses mean(|down2|): down2 never touches HBM.

constexpr int THREADS = 256;
constexpr int TC = 32, TR = 16;       // down outputs per tile
constexpr int ROWS = 2*TR + 3;        // 35 staged input rows
constexpr int COLS = 2*TC + 8;        // 72-float row stride (16B halo align)
constexpr int SEG4 = COLS/4;          // 18 float4 per row
constexpr int OPS  = 12;              // wave-ops per array (12*64=768 >= 35*18=630)
constexpr int OPW  = OPS/4;           // 3 ops per wave per array (UNIFORM)
constexpr int BUFF = OPS*64*4;        // 3072 floats = 12 KB per buffer
constexpr int HR   = 11;              // h rows per wave (4 down rows + halo)

__device__ inline void gload_lds16(const float* g, float* l) {
    auto g1 = (const __attribute__((address_space(1))) void*)g;
    auto l3 = (__attribute__((address_space(3))) void*)l;
    __builtin_amdgcn_global_load_lds(g1, l3, 16, 0, 0);
}

template <int MW, bool FUSE, bool LAST, bool WRITE_DOWN>
__global__ __launch_bounds__(THREADS, MW)
void lap_level(const float* __restrict__ A,    // x (lvl0) or cur
               const float* __restrict__ Bp,   // t (lvl0) or nullptr
               const float* __restrict__ w25,  // 5x5 gaussian (channel 0)
               float* __restrict__ down,       // H/2 x W/2 (if WRITE_DOWN)
               float* __restrict__ P,          // partials P[lvl*8+s], [24+s]
               int H, int W, int ntx, int nty, int ntiles, int K, int level)
{
    __shared__ __align__(16) float sA[3][BUFF];
    __shared__ __align__(16) float sB[3][FUSE ? BUFF : 4];
    __shared__ float sdH[4][HR*TC];
    __shared__ float wsl[4], wsd[4];

    const int tid = threadIdx.x;
    const int wv = tid >> 6, lane = tid & 63;
    const int Hd = H >> 1, Wd = W >> 1;
    const int ntxy = ntx * nty;

    // exact 1D factor: g_i = row-sum of w25 (k = g g^T since sum k = T^2)
    float g0, g1v, g2, g3, g4;
    {
        float gg[5];
#pragma unroll
        for (int i = 0; i < 5; ++i) {
            float s = 0.f;
#pragma unroll
            for (int j = 0; j < 5; ++j) s += w25[i*5 + j];
            gg[i] = s;
        }
        g0 = gg[0]; g1v = gg[1]; g2 = gg[2]; g3 = gg[3]; g4 = gg[4];
    }

    // per-wave staging geometry (iteration-invariant). Wave wv owns ops
    // j = wv*3..wv*3+2; padded ops (idx4 >= 630) re-read clamped row 34.
    int ru[OPW], cu[OPW], lo[OPW];
#pragma unroll
    for (int u = 0; u < OPW; ++u) {
        const int j = wv*OPW + u;
        const int idx4 = j*64 + lane;
        const int r = idx4 / SEG4;
        cu[u] = 4*(idx4 - r*SEG4);
        ru[u] = r > ROWS-1 ? ROWS-1 : r;
        lo[u] = j*256;                 // wave-uniform LDS base (float idx)
    }

    const int t0 = blockIdx.x * K;
    const int t1 = (t0 + K < ntiles) ? t0 + K : ntiles;
    float lsum = 0.f, dsum = 0.f;

    auto stage = [&](int t, int pp) {
        const int n  = t / ntxy;
        const int rem = t - n*ntxy;
        const int tx = rem / nty, ty = rem - (rem/nty)*nty;  // ty FASTEST
        const int gy0 = 2*ty*TR - 2, gx0 = 2*tx*TC - 4;
        const size_t ib = (size_t)n * H * W;
#pragma unroll
        for (int u = 0; u < OPW; ++u) {
            int gy = gy0 + ru[u]; gy = gy < 0 ? 0 : (gy > H-1 ? H-1 : gy);
            int gx = gx0 + cu[u]; gx = gx < 0 ? 0 : (gx > W-4 ? W-4 : gx);
            const size_t off = ib + (size_t)gy*W + gx;
            gload_lds16(A + off, &sA[pp][lo[u]]);
            if constexpr (FUSE) gload_lds16(Bp + off, &sB[pp][lo[u]]);
        }
    };

    auto compute = [&](int t, int pp) {
        const int n  = t / ntxy;
        const int rem = t - n*ntxy;
        const int tx = rem / nty, ty = rem - (rem/nty)*nty;
        const float* ax = sA[pp];
        const float* bx = FUSE ? sB[pp] : sA[pp];
        float* hh = sdH[wv];
        const int hb = 8*wv;                 // wave's input-row base
        const bool txL = (tx == 0), txR = (tx == ntx-1);

        // h-pass: 11 rows x 32 even-cols per wave; edge taps zeroed
#pragma unroll
        for (int k = 0; k < (HR*TC + 63)/64; ++k) {
            const int idx = lane + 64*k;
            if (idx < HR*TC) {
                const int hr = idx >> 5, hc = idx & 31;
                const float gl0 = (txL & (hc == 0))  ? 0.f : g0;
                const float gl1 = (txL & (hc == 0))  ? 0.f : g1v;
                const float gr4 = (txR & (hc == 31)) ? 0.f : g4;
                const float* pa = &ax[(hb+hr)*COLS + 2*hc + 2];
                float a0 = pa[0], a1 = pa[1], a2 = pa[2], a3 = pa[3], a4 = pa[4];
                if constexpr (FUSE) {
                    const float* pb = &bx[(hb+hr)*COLS + 2*hc + 2];
                    a0 -= pb[0]; a1 -= pb[1]; a2 -= pb[2]; a3 -= pb[3]; a4 -= pb[4];
                }
                float h = gl0*a0;
                h = fmaf(gl1, a1, h); h = fmaf(g2, a2, h);
                h = fmaf(g3, a3, h);  h = fmaf(gr4, a4, h);
                hh[hr*TC + hc] = h;
            }
        }
        // v-pass: 2 outputs/lane; top/bottom taps zeroed at image edges
        const int ccx = lane & 31, rsub = lane >> 5;
#pragma unroll
        for (int q = 0; q < 2; ++q) {
            const int lr = rsub + 2*q;                  // 0..3
            const bool mt = (ty == 0) & (wv == 0) & (lr == 0);
            const bool mb = (ty == nty-1) & (wv == 3) & (lr == 3);
            const float v0 = mt ? 0.f : g0, v1 = mt ? 0.f : g1v;
            const float v4 = mb ? 0.f : g4;
            float acc = v0*hh[(2*lr)*TC + ccx];
            acc = fmaf(v1, hh[(2*lr+1)*TC + ccx], acc);
            acc = fmaf(g2, hh[(2*lr+2)*TC + ccx], acc);
            acc = fmaf(g3, hh[(2*lr+3)*TC + ccx], acc);
            acc = fmaf(v4, hh[(2*lr+4)*TC + ccx], acc);
            if constexpr (WRITE_DOWN) {
                const int gr = ty*TR + 4*wv + lr;
                down[(size_t)n*Hd*Wd + (size_t)gr*Wd + (tx*TC + ccx)] = acc;
            }
            // lap = cur - up(down): 2x2 block (always interior to stage)
            const int cb = (hb + 2*lr + 2)*COLS + 2*ccx + 4;
            float c0 = ax[cb], c1 = ax[cb+1], c2 = ax[cb+COLS], c3 = ax[cb+COLS+1];
            if constexpr (FUSE) {
                c0 -= bx[cb];      c1 -= bx[cb+1];
                c2 -= bx[cb+COLS]; c3 -= bx[cb+COLS+1];
            }
            lsum += fabsf(c0-acc) + fabsf(c1-acc) + fabsf(c2-acc) + fabsf(c3-acc);
            if constexpr (LAST) dsum += fabsf(acc);
        }
    };

    if (t0 < t1) {
        stage(t0, 0);
        if (t0 + 1 < t1) stage(t0 + 1, 1);
        int pc = 0, ps = 2;                // buf of tile t / of tile t+2
        for (int t = t0; t < t1; ++t) {
            __builtin_amdgcn_s_barrier();  // all waves done reading buf t-1
            if (t + 2 < t1) stage(t + 2, ps);   // overwrites buf of t-1
            const int ahead = (t1-1-t) < 2 ? (t1-1-t) : 2;
            // per-wave counted wait: retire only tile t's ops (6 FUSE / 3)
            if constexpr (FUSE) {
                if (ahead == 2)      asm volatile("s_waitcnt vmcnt(12)" ::: "memory");
                else if (ahead == 1) asm volatile("s_waitcnt vmcnt(6)"  ::: "memory");
                else                 asm volatile("s_waitcnt vmcnt(0)"  ::: "memory");
            } else {
                if (ahead == 2)      asm volatile("s_waitcnt vmcnt(6)"  ::: "memory");
                else if (ahead == 1) asm volatile("s_waitcnt vmcnt(3)"  ::: "memory");
                else                 asm volatile("s_waitcnt vmcnt(0)"  ::: "memory");
            }
            __builtin_amdgcn_sched_barrier(0);
            __builtin_amdgcn_s_barrier();  // ALL waves' tile-t loads landed
            compute(t, pc);
            pc = pc == 2 ? 0 : pc + 1;
            ps = ps == 2 ? 0 : ps + 1;
        }
    }

    // ---- wave reduce -> block reduce -> one spread atomic per level ----
#pragma unroll
    for (int off = 32; off > 0; off >>= 1) {
        lsum += __shfl_down(lsum, off);
        if (LAST) dsum += __shfl_down(dsum, off);
    }
    __syncthreads();
    if (lane == 0) { wsl[wv] = lsum; if (LAST) wsd[wv] = dsum; }
    __syncthreads();
    if (tid == 0) {
        atomicAdd(&P[level*8 + (blockIdx.x & 7)], wsl[0]+wsl[1]+wsl[2]+wsl[3]);
        if (LAST)
            atomicAdd(&P[24 + (blockIdx.x & 7)], wsd[0]+wsd[1]+wsd[2]+wsd[3]);
    }
}

__global__ void finalize_kernel(const float* __restrict__ P,
                                float* __restrict__ out,
                                float inv0, float inv1, float inv2, float inv3)
{
    float s0 = 0.f, s1 = 0.f, s2 = 0.f, s3 = 0.f;
#pragma unroll
    for (int i = 0; i < 8; ++i) {
        s0 += P[i]; s1 += P[8+i]; s2 += P[16+i]; s3 += P[24+i];
    }
    out[0] = s0*inv0 + s1*inv1 + s2*inv2 + s3*inv3;
}

extern "C" void kernel_launch(void* const* d_in, const int* in_sizes, int n_in,
                              void* d_out, int out_size, void* d_ws, size_t ws_size,
                              hipStream_t stream)
{
    const float* x   = (const float*)d_in[0];
    const float* t   = (const float*)d_in[1];
    const float* ker = (const float*)d_in[2];  // (13,1,5,5); channels identical
    float* out = (float*)d_out;

    constexpr int B = 16, C = 13, H = 512, W = 512;
    constexpr int N = B * C;  // 208 image-channels

    // ws: [32 floats partials (pad 256B)] [down0: N*256*256] [down1: N*128*128]
    float* P     = (float*)d_ws;
    float* down0 = (float*)((char*)d_ws + 256);
    float* down1 = down0 + (size_t)N * (H/2) * (W/2);

    hipMemsetAsync(P, 0, 32 * sizeof(float), stream);

    dim3 blk(THREADS);
    // level 0: FUSE. LDS ~79.4 KB -> 2 blocks/CU -> grid 512.
    {
        const int ntx = (W/2)/TC, nty = (H/2)/TR;      // 8 x 16 -> 128 tiles/img
        const int nt = ntx*nty*N;                      // 26624
        const int grid = 512, K = (nt + grid - 1)/grid;        // 52
        lap_level<2, true, false, true><<<grid, blk, 0, stream>>>(
            x, t, ker, down0, P, H, W, ntx, nty, nt, K, 0);
    }
    // level 1: LDS ~42.6 KB -> 3 blocks/CU -> grid 768.
    {
        const int ntx = (W/4)/TC, nty = (H/4)/TR;      // 4 x 8
        const int nt = ntx*nty*N;                      // 6656
        const int grid = 768, K = (nt + grid - 1)/grid;        // 9
        lap_level<3, false, false, true><<<grid, blk, 0, stream>>>(
            down0, nullptr, ker, down1, P, H/2, W/2, ntx, nty, nt, K, 1);
    }
    // level 2: 128 -> 64 in-register; fuses mean(|down2|).
    {
        const int ntx = (W/8)/TC, nty = (H/8)/TR;      // 2 x 4
        const int nt = ntx*nty*N;                      // 1664
        const int grid = 768, K = (nt + grid - 1)/grid;        // 3
        lap_level<3, false, true, false><<<grid, blk, 0, stream>>>(
            down1, nullptr, ker, nullptr, P, H/4, W/4, ntx, nty, nt, K, 2);
    }

    const float inv0 = 1.0f / ((float)N * H * W);
    const float inv1 = 1.0f / ((float)N * (H/2) * (W/2));
    const float inv2 = 1.0f / ((float)N * (H/4) * (W/4));
    const float inv3 = 1.0f / ((float)N * (H/8) * (W/8));
    finalize_kernel<<<1, 1, 0, stream>>>(P, out, inv0, inv1, inv2, inv3);
}

// Round 14
// 217.803 us; speedup vs baseline: 1.4920x; 1.0187x over previous
//
#include <hip/hip_runtime.h>

// LaplacianPyramidLoss: loss = sum_l mean(|pyr(x)[l] - pyr(t)[l]|)
// Linearity: pyr(x)-pyr(t) = pyr(x-t) -> ONE pyramid of d=x-t.
// R14 = R10 (issue-early register double-buffer, T14) WITHOUT the
// __launch_bounds__(256,6) register cap that forced every prefetch
// register to scratch (R10: WRITE_SIZE 480 MB of spills, yet the memory
// system sustained 3.96 TB/s -- proving the flow pattern works). R13's
// period arithmetic showed the real regime: period = max(stage, compute
// +sync); letting the compiler keep ~100 VGPR removes the spill while
// LDS (26 KB) sets occupancy ~5-6 blocks/CU. d = x-t folded at ds_write
// (halves LDS bytes + h-pass reads). Level 2 fuses mean(|down2|).

constexpr int THREADS = 256;
constexpr int TC = 32;              // down cols per tile
constexpr int TR = 16;              // down rows per tile
constexpr int ROWS = 2*TR + 3;      // 35 input rows (5x5 halo)
constexpr int COLS = 2*TC + 8;      // 72 float row stride (16B-aligned halo)
constexpr int SEG4 = COLS/4;        // 18 float4 per row
constexpr int TOT4 = ROWS*SEG4;     // 630 float4 per tile
constexpr int KLOAD = (TOT4 + THREADS - 1)/THREADS;   // 3 float4/thread
constexpr int HR = 11;              // h rows per wave (4 down rows + halo)
constexpr int NBLK = 1280;          // persistent: ~5 blocks/CU x 256 CU

template <bool FUSE, bool LAST, bool WRITE_DOWN>
__global__ __launch_bounds__(THREADS)   // NO min-blocks cap -> no spill
void lap_level(const float* __restrict__ A,    // x (lvl0) or cur
               const float* __restrict__ Bp,   // t (lvl0) or nullptr
               const float* __restrict__ w25,  // 5x5 gaussian (channel 0)
               float* __restrict__ down,       // H/2 x W/2 (if WRITE_DOWN)
               float* __restrict__ P,          // partials P[lvl*8+s], [24+s]
               int H, int W, int ntx, int ntxy, int ntiles, int level)
{
    __shared__ __align__(16) float sdD[2][ROWS*COLS];  // 20.2 KB ping-pong
    __shared__ float sdH[4][HR*TC];                    // 5.6 KB per-wave h
    __shared__ float wsl[4], wsd[4];

    const int tid  = threadIdx.x;
    const int wv   = tid >> 6, lane = tid & 63;
    const int Hd = H >> 1, Wd = W >> 1;

    // exact 1D factor: g_i = row-sum of w25 (k = g g^T since sum k = T^2)
    float g0, g1, g2, g3, g4;
    {
        float gg[5];
#pragma unroll
        for (int i = 0; i < 5; ++i) {
            float s = 0.f;
#pragma unroll
            for (int j = 0; j < 5; ++j) s += w25[i*5 + j];
            gg[i] = s;
        }
        g0 = gg[0]; g1 = gg[1]; g2 = gg[2]; g3 = gg[3]; g4 = gg[4];
    }

    // hoisted staging coords (tid-only)
    int rr_[KLOAD], cc_[KLOAD];
#pragma unroll
    for (int k = 0; k < KLOAD; ++k) {
        const int idx = tid + k*THREADS;
        rr_[k] = idx / SEG4;
        cc_[k] = idx - rr_[k]*SEG4;
    }

    float lsum = 0.f, dsum = 0.f;
    float4 va0[KLOAD], vb0[KLOAD], va1[KLOAD], vb1[KLOAD];
    int cur = blockIdx.x;
    int p = 0;

    auto issue = [&](int t, float4 (&va)[KLOAD], float4 (&vb)[KLOAD]) {
        const int n   = t / ntxy;
        const int rem = t - n*ntxy;
        const int ty  = rem / ntx;
        const int tx  = rem - ty*ntx;
        const int gy0 = 2*ty*TR - 2;
        const int gx0 = 2*tx*TC - 4;        // 16B-aligned halo start
        const size_t ib = (size_t)n * H * W;
#pragma unroll
        for (int k = 0; k < KLOAD; ++k) {
            const int gy = gy0 + rr_[k];
            const int gx = gx0 + 4*cc_[k];  // W%4==0 -> float4 all-in/all-out
            const bool ok = (rr_[k] < ROWS) & ((unsigned)gy < (unsigned)H)
                                            & ((unsigned)gx < (unsigned)W);
            va[k] = make_float4(0.f, 0.f, 0.f, 0.f);
            if (FUSE) vb[k] = make_float4(0.f, 0.f, 0.f, 0.f);
            if (ok) {
                const size_t off = ib + (size_t)gy*W + gx;
                va[k] = *(const float4*)(A + off);
                if (FUSE) vb[k] = *(const float4*)(Bp + off);
            }
        }
    };

    auto write_lds = [&](int pp, float4 (&va)[KLOAD], float4 (&vb)[KLOAD]) {
#pragma unroll
        for (int k = 0; k < KLOAD; ++k) {
            if (rr_[k] < ROWS) {
                float4 d = va[k];
                if (FUSE) { d.x -= vb[k].x; d.y -= vb[k].y;
                            d.z -= vb[k].z; d.w -= vb[k].w; }
                *(float4*)&sdD[pp][rr_[k]*COLS + 4*cc_[k]] = d;
            }
        }
    };

    auto compute = [&](int t, int pp) {
        const int n   = t / ntxy;
        const int rem = t - n*ntxy;
        const int ty  = rem / ntx;
        const int tx  = rem - ty*ntx;
        const int oy0 = ty*TR, ox0 = tx*TC;
        const float* dd = sdD[pp];
        float* hh = sdH[wv];
        const int hb = 8*wv;            // wave's input-row base (4 down rows)

        // h-pass: 11 rows x 32 even-cols, wave-private region
#pragma unroll
        for (int k = 0; k < (HR*TC + 63)/64; ++k) {
            const int idx = lane + 64*k;
            if (idx < HR*TC) {
                const int hr = idx >> 5, hc = idx & 31;
                const float* dr = &dd[(hb + hr)*COLS + 2*hc + 2];
                float a = g0*dr[0];
                a = fmaf(g1, dr[1], a);
                a = fmaf(g2, dr[2], a);
                a = fmaf(g3, dr[3], a);
                a = fmaf(g4, dr[4], a);
                hh[hr*TC + hc] = a;
            }
        }
        // v-pass: 2 outputs per lane (rows rsub, rsub+2 of wave's 4)
        const int ccx = lane & 31, rsub = lane >> 5;
#pragma unroll
        for (int q = 0; q < 2; ++q) {
            const int lr = rsub + 2*q;                // 0..3
            float acc = g0*hh[(2*lr)*TC + ccx];
            acc = fmaf(g1, hh[(2*lr+1)*TC + ccx], acc);
            acc = fmaf(g2, hh[(2*lr+2)*TC + ccx], acc);
            acc = fmaf(g3, hh[(2*lr+3)*TC + ccx], acc);
            acc = fmaf(g4, hh[(2*lr+4)*TC + ccx], acc);
            if (WRITE_DOWN) {
                const int gr = oy0 + 4*wv + lr;
                down[(size_t)n*Hd*Wd + (size_t)gr*Wd + (ox0 + ccx)] = acc;
            }
            // lap = cur - up(down): 2x2 input block of this down value
            const float* cr = &dd[(hb + 2*lr + 2)*COLS + 2*ccx + 4];
            lsum += fabsf(cr[0]    - acc) + fabsf(cr[1]      - acc)
                  + fabsf(cr[COLS] - acc) + fabsf(cr[COLS+1] - acc);
            if (LAST) dsum += fabsf(acc);
        }
    };

    if (cur < ntiles) {
        issue(cur, va0, vb0);
        bool useBuf0 = true;
        for (;;) {
            const int nxt = cur + NBLK;     // gridDim.x == NBLK
            // T14: issue NEXT tile FIRST, then write cur's registers.
            // Scoreboard emits vmcnt(6): next's loads stay in flight while
            // cur's (aged a full loop period) are consumed by ds_write.
            if (useBuf0) {
                if (nxt < ntiles) issue(nxt, va1, vb1);
                write_lds(p, va0, vb0);
            } else {
                if (nxt < ntiles) issue(nxt, va0, vb0);
                write_lds(p, va1, vb1);
            }
            asm volatile("s_waitcnt lgkmcnt(0)" ::: "memory");
            __builtin_amdgcn_s_barrier();
            __builtin_amdgcn_sched_barrier(0);

            compute(cur, p);

            if (nxt >= ntiles) break;
            cur = nxt; p ^= 1; useBuf0 = !useBuf0;
        }
    }

    // ---- wave reduce -> block reduce -> one spread atomic per level ----
#pragma unroll
    for (int off = 32; off > 0; off >>= 1) {
        lsum += __shfl_down(lsum, off);
        if (LAST) dsum += __shfl_down(dsum, off);
    }
    if (lane == 0) { wsl[wv] = lsum; if (LAST) wsd[wv] = dsum; }
    __syncthreads();
    if (tid == 0) {
        atomicAdd(&P[level*8 + (blockIdx.x & 7)], wsl[0]+wsl[1]+wsl[2]+wsl[3]);
        if (LAST)
            atomicAdd(&P[24 + (blockIdx.x & 7)], wsd[0]+wsd[1]+wsd[2]+wsd[3]);
    }
}

__global__ void finalize_kernel(const float* __restrict__ P,
                                float* __restrict__ out,
                                float inv0, float inv1, float inv2, float inv3)
{
    float s0 = 0.f, s1 = 0.f, s2 = 0.f, s3 = 0.f;
#pragma unroll
    for (int i = 0; i < 8; ++i) {
        s0 += P[i]; s1 += P[8+i]; s2 += P[16+i]; s3 += P[24+i];
    }
    out[0] = s0*inv0 + s1*inv1 + s2*inv2 + s3*inv3;
}

extern "C" void kernel_launch(void* const* d_in, const int* in_sizes, int n_in,
                              void* d_out, int out_size, void* d_ws, size_t ws_size,
                              hipStream_t stream)
{
    const float* x   = (const float*)d_in[0];
    const float* t   = (const float*)d_in[1];
    const float* ker = (const float*)d_in[2];  // (13,1,5,5); channels identical
    float* out = (float*)d_out;

    constexpr int B = 16, C = 13, H = 512, W = 512;
    constexpr int N = B * C;  // 208 image-channels

    // ws: [32 floats partials (pad 256B)] [down0: N*256*256] [down1: N*128*128]
    float* P     = (float*)d_ws;
    float* down0 = (float*)((char*)d_ws + 256);
    float* down1 = down0 + (size_t)N * (H/2) * (W/2);

    hipMemsetAsync(P, 0, 32 * sizeof(float), stream);

    dim3 blk(THREADS);
    // level 0: d = x-t (fused at LDS write), 512 -> down0 256
    {
        const int ntx = (W/2)/TC, ntxy = ntx * ((H/2)/TR);   // 8 x 16 = 128
        lap_level<true, false, true><<<dim3(NBLK), blk, 0, stream>>>(
            x, t, ker, down0, P, H, W, ntx, ntxy, ntxy*N, 0);
    }
    // level 1: down0 256 -> down1 128 (down0 is L3-resident)
    {
        const int ntx = (W/4)/TC, ntxy = ntx * ((H/4)/TR);   // 4 x 8 = 32
        lap_level<false, false, true><<<dim3(NBLK), blk, 0, stream>>>(
            down0, nullptr, ker, down1, P, H/2, W/2, ntx, ntxy, ntxy*N, 1);
    }
    // level 2: down1 128 -> 64 (in-register), fuses level-3 mean(|down2|)
    {
        const int ntx = (W/8)/TC, ntxy = ntx * ((H/8)/TR);   // 2 x 4 = 8
        lap_level<false, true, false><<<dim3(NBLK), blk, 0, stream>>>(
            down1, nullptr, ker, nullptr, P, H/4, W/4, ntx, ntxy, ntxy*N, 2);
    }

    const float inv0 = 1.0f / ((float)N * H * W);
    const float inv1 = 1.0f / ((float)N * (H/2) * (W/2));
    const float inv2 = 1.0f / ((float)N * (H/4) * (W/4));
    const float inv3 = 1.0f / ((float)N * (H/8) * (W/8));
    finalize_kernel<<<1, 1, 0, stream>>>(P, out, inv0, inv1, inv2, inv3);
}